// Round 1
// baseline (1070.415 us; speedup 1.0000x reference)
//
#include <hip/hip_runtime.h>
#include <hip/hip_bf16.h>

#define D_DIM 256
#define BM 128
#define BKC 128
#define DC 32

// ---------------- ws layout ----------------
// [0      .. 4096)  esq   (K floats)
// [4096   .. 8192)  counts (K floats)
// [8192   .. 8196)  lossAcc (1 float)
// [12288  .. +N*4)  idx   (N ints)

__global__ __launch_bounds__(64) void esq_kernel(const float* __restrict__ emb,
                                                 float* __restrict__ esq) {
    int k = blockIdx.x;
    int lane = threadIdx.x;
    float4 v = reinterpret_cast<const float4*>(emb + (size_t)k * D_DIM)[lane];
    float s = v.x * v.x + v.y * v.y + v.z * v.z + v.w * v.w;
    #pragma unroll
    for (int off = 32; off; off >>= 1) s += __shfl_down(s, off, 64);
    if (lane == 0) esq[k] = s;
}

// Fused score (||e||^2 - 2 z.e) + running argmin.
// Block tile: BM=128 rows x BKC=128 codes; 256 threads as 16(tx: codes) x 16(ty: rows),
// 8x8 register micro-tile per thread. D staged in DC=32 chunks, transposed in LDS.
__global__ __launch_bounds__(256, 4) void argmin_kernel(
    const float* __restrict__ z, const float* __restrict__ emb,
    const float* __restrict__ esq, int* __restrict__ out_idx, int K) {
    __shared__ float zt[DC][BM];
    __shared__ float et[DC][BKC];

    const int tid = threadIdx.x;
    const int tx = tid & 15;   // code dimension
    const int ty = tid >> 4;   // row dimension
    const int n0 = blockIdx.x * BM;

    const int lrow = tid >> 1;         // staging row 0..127
    const int lcol = (tid & 1) << 4;   // staging d-offset 0 or 16

    float best[8];
    int bidx[8];
    #pragma unroll
    for (int i = 0; i < 8; ++i) { best[i] = 3.4e38f; bidx[i] = 0; }

    const float* zbase = z + (size_t)(n0 + lrow) * D_DIM + lcol;

    for (int kc = 0; kc < K; kc += BKC) {
        const float* ebase = emb + (size_t)(kc + lrow) * D_DIM + lcol;
        float acc[8][8];
        #pragma unroll
        for (int i = 0; i < 8; ++i)
            #pragma unroll
            for (int j = 0; j < 8; ++j) acc[i][j] = 0.f;

        for (int dc = 0; dc < D_DIM; dc += DC) {
            float4 zv[4], ev[4];
            #pragma unroll
            for (int u = 0; u < 4; ++u) {
                zv[u] = *reinterpret_cast<const float4*>(zbase + dc + 4 * u);
                ev[u] = *reinterpret_cast<const float4*>(ebase + dc + 4 * u);
            }
            __syncthreads();   // previous phase's LDS reads complete
            #pragma unroll
            for (int u = 0; u < 4; ++u) {
                zt[lcol + 4 * u + 0][lrow] = zv[u].x;
                zt[lcol + 4 * u + 1][lrow] = zv[u].y;
                zt[lcol + 4 * u + 2][lrow] = zv[u].z;
                zt[lcol + 4 * u + 3][lrow] = zv[u].w;
                et[lcol + 4 * u + 0][lrow] = ev[u].x;
                et[lcol + 4 * u + 1][lrow] = ev[u].y;
                et[lcol + 4 * u + 2][lrow] = ev[u].z;
                et[lcol + 4 * u + 3][lrow] = ev[u].w;
            }
            __syncthreads();
            #pragma unroll 8
            for (int d = 0; d < DC; ++d) {
                float4 za = *reinterpret_cast<const float4*>(&zt[d][ty * 8]);
                float4 zb = *reinterpret_cast<const float4*>(&zt[d][ty * 8 + 4]);
                float4 ea = *reinterpret_cast<const float4*>(&et[d][tx * 8]);
                float4 eb = *reinterpret_cast<const float4*>(&et[d][tx * 8 + 4]);
                float zr[8] = {za.x, za.y, za.z, za.w, zb.x, zb.y, zb.z, zb.w};
                float er[8] = {ea.x, ea.y, ea.z, ea.w, eb.x, eb.y, eb.z, eb.w};
                #pragma unroll
                for (int i = 0; i < 8; ++i)
                    #pragma unroll
                    for (int j = 0; j < 8; ++j)
                        acc[i][j] = fmaf(zr[i], er[j], acc[i][j]);
            }
        }
        // scores + running argmin (strict < keeps earliest k on ties)
        #pragma unroll
        for (int j = 0; j < 8; ++j) {
            int k = kc + tx * 8 + j;
            float ek = esq[k];
            #pragma unroll
            for (int i = 0; i < 8; ++i) {
                float s = fmaf(-2.f, acc[i][j], ek);
                if (s < best[i]) { best[i] = s; bidx[i] = k; }
            }
        }
    }

    // reduce across the 16 tx-lanes (same wave, 16-lane groups)
    #pragma unroll
    for (int i = 0; i < 8; ++i) {
        float b = best[i];
        int bi = bidx[i];
        #pragma unroll
        for (int off = 8; off; off >>= 1) {
            float ob = __shfl_xor(b, off, 16);
            int obi = __shfl_xor(bi, off, 16);
            if (ob < b || (ob == b && obi < bi)) { b = ob; bi = obi; }
        }
        if (tx == 0) out_idx[n0 + ty * 8 + i] = bi;
    }
}

// One wave per row: gather codeword, write straight-through output, accumulate
// commitment loss and code counts.
__global__ __launch_bounds__(256) void gather_kernel(
    const float* __restrict__ z, const float* __restrict__ emb,
    const int* __restrict__ idx, float* __restrict__ q,
    float* __restrict__ counts, float* __restrict__ lossAcc, int N) {
    const int lane = threadIdx.x & 63;
    const int wave = threadIdx.x >> 6;
    const int wavesPerBlock = blockDim.x >> 6;
    const int gw = blockIdx.x * wavesPerBlock + wave;
    const int nw = gridDim.x * wavesPerBlock;
    float ls = 0.f;
    for (int n = gw; n < N; n += nw) {
        int k = idx[n];
        const float* e = emb + (size_t)k * D_DIM;
        const float* zr = z + (size_t)n * D_DIM;
        float* qr = q + (size_t)n * D_DIM;
        #pragma unroll
        for (int j = 0; j < 4; ++j) {
            int d = lane + (j << 6);
            float evv = e[d];
            float zvv = zr[d];
            float diff = evv - zvv;
            qr[d] = zvv + diff;  // straight-through: z + (q - z), mimics reference fp32 ops
            ls = fmaf(diff, diff, ls);
        }
        if (lane == 0) atomicAdd(&counts[k], 1.0f);
    }
    #pragma unroll
    for (int off = 32; off; off >>= 1) ls += __shfl_down(ls, off, 64);
    __shared__ float red[8];
    if (lane == 0) red[wave] = ls;
    __syncthreads();
    if (threadIdx.x == 0) {
        float t = 0.f;
        for (int w = 0; w < wavesPerBlock; ++w) t += red[w];
        atomicAdd(lossAcc, t);
    }
}

__global__ __launch_bounds__(256) void finalize_kernel(
    const float* __restrict__ counts, const float* __restrict__ lossAcc,
    float* __restrict__ out_loss, float* __restrict__ out_perp,
    int K, float invN, float invND) {
    __shared__ float red[256];
    int t = threadIdx.x;
    float h = 0.f;
    for (int k = t; k < K; k += 256) {
        float p = counts[k] * invN;
        h += p * logf(p + 1e-10f);
    }
    red[t] = h;
    __syncthreads();
    for (int s = 128; s; s >>= 1) {
        if (t < s) red[t] += red[t + s];
        __syncthreads();
    }
    if (t == 0) {
        out_loss[0] = 0.25f * lossAcc[0] * invND;
        out_perp[0] = expf(-red[0]);
    }
}

extern "C" void kernel_launch(void* const* d_in, const int* in_sizes, int n_in,
                              void* d_out, int out_size, void* d_ws, size_t ws_size,
                              hipStream_t stream) {
    const float* z = (const float*)d_in[0];
    const float* emb = (const float*)d_in[1];
    const int N = in_sizes[0] / D_DIM;   // 131072
    const int K = in_sizes[1] / D_DIM;   // 1024
    float* out = (float*)d_out;

    char* ws = (char*)d_ws;
    float* esq = (float*)(ws);
    float* counts = (float*)(ws + 4096);
    float* lossAcc = (float*)(ws + 8192);
    int* idx = (int*)(ws + 12288);

    // zero counts + loss accumulator (ws is poisoned before every launch)
    hipMemsetAsync(ws + 4096, 0, 4096 + 64, stream);

    esq_kernel<<<K, 64, 0, stream>>>(emb, esq);
    argmin_kernel<<<N / BM, 256, 0, stream>>>(z, emb, esq, idx, K);
    gather_kernel<<<2048, 256, 0, stream>>>(z, emb, idx, out + 1, counts, lossAcc, N);
    finalize_kernel<<<1, 256, 0, stream>>>(counts, lossAcc, out,
                                           out + 1 + (size_t)N * D_DIM, K,
                                           1.0f / (float)N, 1.0f / ((float)N * (float)D_DIM));
}